// Round 14
// baseline (110.039 us; speedup 1.0000x reference)
//
#include <hip/hip_runtime.h>

typedef float f4 __attribute__((ext_vector_type(4)));

#define N_SEL   8192
#define N_FEAT  256
#define K_SUB   256
#define N_PERS  4
#define E_FULL  262144
#define E_RAW   262144
#define N_TOTAL 8192
#define EPSILON 0.5f
#define LAMB1   0.5f

// Workspace layout:
#define WS_SCORE_OFF  (128 * 1024)                    // score[K_SUB] f32
#define WS_CNT_OFF    (132 * 1024)                    // pass counter i32
#define WS_XQ_OFF     (256 * 1024)                    // xq[N_SEL][256] fp8 (2 MB)
#define WS_LIST_OFF   (WS_XQ_OFF + 2 * 1024 * 1024)   // list[E_FULL] int2 (2 MB)

// ---- K1: one wave per node: 4 inverse norms + fp8 convert + score + cnt=0 ----
__global__ __launch_bounds__(256) void prep_kernel(const f4* __restrict__ x4,
                                                   const f4* __restrict__ w4,
                                                   f4* __restrict__ invn4,
                                                   unsigned int* __restrict__ xq,
                                                   const float* __restrict__ s,
                                                   const int* __restrict__ belong,
                                                   float* __restrict__ score,
                                                   int* __restrict__ cnt) {
    __shared__ float sv[K_SUB];
    __shared__ int bv[K_SUB];
    int gid = blockIdx.x * 256 + threadIdx.x;
    int n = gid >> 6;                    // node id
    int lane = threadIdx.x & 63;

    f4 xv = x4[(size_t)n * 64 + lane];

    int pk = 0;
    pk = __builtin_amdgcn_cvt_pk_fp8_f32(xv.x, xv.y, pk, false);
    pk = __builtin_amdgcn_cvt_pk_fp8_f32(xv.z, xv.w, pk, true);
    xq[(size_t)n * 64 + lane] = (unsigned int)pk;

    f4 ssv;
    #pragma unroll
    for (int p = 0; p < 4; ++p) {
        f4 h = xv * w4[p * 64 + lane];
        float ss = h.x * h.x + h.y * h.y + h.z * h.z + h.w * h.w;
        #pragma unroll
        for (int off = 32; off; off >>= 1) ss += __shfl_xor(ss, off);
        ssv[p] = ss;
    }
    if (lane == 0) {
        f4 r;
        r.x = 1.0f / (sqrtf(ssv.x) + 1e-12f);
        r.y = 1.0f / (sqrtf(ssv.y) + 1e-12f);
        r.z = 1.0f / (sqrtf(ssv.z) + 1e-12f);
        r.w = 1.0f / (sqrtf(ssv.w) + 1e-12f);
        invn4[n] = r;
    }

    if (gid == 0) *cnt = 0;

    if (blockIdx.x == 0) {
        int t = threadIdx.x;
        sv[t] = s[t];
        bv[t] = belong[t];
        __syncthreads();
        int myb = bv[t];
        float sum = 0.0f;
        for (int k = 0; k < K_SUB; ++k)
            if (bv[k] == myb) sum += sv[k];
        score[t] = sv[t] / sum;
    }
}

// ---- K2: PURE zero stream — the cleanest write-roofline probe. Grid-stride
// f4 stores, 1 KB per wave-instruction, nothing else on the clock. ----
__global__ __launch_bounds__(256) void zero_kernel(f4* __restrict__ p) {
    int gid = blockIdx.x * 256 + threadIdx.x;       // 4096 blocks
    f4 z = (f4)0.0f;
    #pragma unroll
    for (int k = 0; k < 16; ++k)                    // 16M f4 total
        p[(size_t)k * 1048576 + gid] = z;
}

// ---- K3: raw-edge atomics (fire-and-forget, no return -> no wait) issued
// FIRST, then the VALU-heavy cosine edge loop — the random-RMW latency hides
// under edge math instead of being its own serialized pass. Zeros are
// complete (kernel boundary). ----
__global__ __launch_bounds__(256) void edge_raw_kernel(float* __restrict__ out,
                                                       const unsigned int* __restrict__ xq,
                                                       const f4* __restrict__ w4,
                                                       const int* __restrict__ fe,
                                                       const int* __restrict__ re,
                                                       const int* __restrict__ sel_batch,
                                                       const f4* __restrict__ invn4,
                                                       const float* __restrict__ score,
                                                       int2* __restrict__ list,
                                                       int* __restrict__ cnt) {
    int b = blockIdx.x;                  // 0..2047
    int t = threadIdx.x;
    int gt = b * 256 + t;                // 0..524287
    int lane = t & 63;
    int w = t >> 6;

    // fire-and-forget raw-edge atomic (first 262144 threads)
    if (gt < E_RAW) {
        int u = re[gt];
        int v = re[E_RAW + gt];
        atomicAdd(&out[(size_t)u * N_TOTAL + v], 1.0f - LAMB1);
    }

    // wave's 32 edges: lanes 0-31 hold i's, lanes 32-63 hold j's
    int ebase = b * 128 + w * 32;
    int myidx = (lane < 32) ? fe[ebase + lane] : fe[E_FULL + ebase + (lane - 32)];

    // per-lane squared weights for dims [4*lane, 4*lane+4), 4 perspectives
    f4 q0 = w4[0 * 64 + lane]; q0 *= q0;
    f4 q1 = w4[1 * 64 + lane]; q1 *= q1;
    f4 q2 = w4[2 * 64 + lane]; q2 *= q2;
    f4 q3 = w4[3 * 64 + lane]; q3 *= q3;

    // prologue: edge 0 operands
    int ci = __shfl(myidx, 0);
    int cj = __shfl(myidx, 32);
    unsigned int xi = xq[(size_t)ci * 64 + lane];
    unsigned int xj = xq[(size_t)cj * 64 + lane];
    f4 ii = invn4[ci];
    f4 ij = invn4[cj];

    #pragma unroll 4
    for (int s = 0; s < 32; ++s) {
        int i = ci, j = cj;
        unsigned int ax = xi, bx = xj;
        f4 aii = ii, aij = ij;
        if (s < 31) {
            ci = __shfl(myidx, s + 1);
            cj = __shfl(myidx, 32 + s + 1);
            xi = xq[(size_t)ci * 64 + lane];
            xj = xq[(size_t)cj * 64 + lane];
            ii = invn4[ci];
            ij = invn4[cj];
        }

        float pd0 = __builtin_amdgcn_cvt_f32_fp8((int)ax, 0) *
                    __builtin_amdgcn_cvt_f32_fp8((int)bx, 0);
        float pd1 = __builtin_amdgcn_cvt_f32_fp8((int)ax, 1) *
                    __builtin_amdgcn_cvt_f32_fp8((int)bx, 1);
        float pd2 = __builtin_amdgcn_cvt_f32_fp8((int)ax, 2) *
                    __builtin_amdgcn_cvt_f32_fp8((int)bx, 2);
        float pd3 = __builtin_amdgcn_cvt_f32_fp8((int)ax, 3) *
                    __builtin_amdgcn_cvt_f32_fp8((int)bx, 3);

        float a0 = fmaf(pd3, q0.w, fmaf(pd2, q0.z, fmaf(pd1, q0.y, pd0 * q0.x)));
        float a1 = fmaf(pd3, q1.w, fmaf(pd2, q1.z, fmaf(pd1, q1.y, pd0 * q1.x)));
        float a2 = fmaf(pd3, q2.w, fmaf(pd2, q2.z, fmaf(pd1, q2.y, pd0 * q2.x)));
        float a3 = fmaf(pd3, q3.w, fmaf(pd2, q3.z, fmaf(pd1, q3.y, pd0 * q3.x)));

        float v = a0 * (aii.x * aij.x) + a1 * (aii.y * aij.y) +
                  a2 * (aii.z * aij.z) + a3 * (aii.w * aij.w);
        v += __shfl_xor(v, 1);
        v += __shfl_xor(v, 2);
        v += __shfl_xor(v, 4);
        v += __shfl_xor(v, 8);
        v += __shfl_xor(v, 16);
        v += __shfl_xor(v, 32);

        if (lane == 0 && i != j) {
            v *= 0.25f;
            if (v > EPSILON) {
                float val = v * score[sel_batch[i]] * LAMB1;
                int idx = atomicAdd(cnt, 1);
                int2 ent;
                ent.x = (i << 13) | j;
                ent.y = __float_as_int(val);
                list[idx] = ent;
            }
        }
    }
}

// ---- K4: dedup'd learned-edge scatter (usually n==0: immediate exit) ----
__global__ __launch_bounds__(256) void finalize_kernel(const int2* __restrict__ list,
                                                       const int* __restrict__ cnt,
                                                       const int* __restrict__ sel_map,
                                                       float* __restrict__ out) {
    int t = blockIdx.x * 256 + threadIdx.x;
    int n = *cnt;
    if (t >= n) return;
    int2 ek = list[t];
    for (int l = 0; l < t; ++l)
        if (list[l].x == ek.x) return;      // first occurrence wins; dups identical
    int i = ek.x >> 13;
    int j = ek.x & (N_SEL - 1);
    atomicAdd(&out[(size_t)sel_map[i] * N_TOTAL + sel_map[j]], __int_as_float(ek.y));
}

extern "C" void kernel_launch(void* const* d_in, const int* in_sizes, int n_in,
                              void* d_out, int out_size, void* d_ws, size_t ws_size,
                              hipStream_t stream) {
    const float* x         = (const float*)d_in[0];
    const float* mw        = (const float*)d_in[1];
    const int* sel_batch   = (const int*)d_in[2];
    const int* sel_map     = (const int*)d_in[3];
    const int* sel_belong  = (const int*)d_in[4];
    const float* sel_score = (const float*)d_in[5];
    const int* fe          = (const int*)d_in[6];
    const int* re          = (const int*)d_in[7];
    float* out             = (float*)d_out;

    char* ws         = (char*)d_ws;
    f4* invn4        = (f4*)ws;
    float* score     = (float*)(ws + WS_SCORE_OFF);
    int* cnt         = (int*)(ws + WS_CNT_OFF);
    unsigned int* xq = (unsigned int*)(ws + WS_XQ_OFF);
    int2* list       = (int2*)(ws + WS_LIST_OFF);

    prep_kernel<<<2048, 256, 0, stream>>>(
        (const f4*)x, (const f4*)mw, invn4, xq, sel_score, sel_belong, score, cnt);
    zero_kernel<<<4096, 256, 0, stream>>>((f4*)out);
    edge_raw_kernel<<<2048, 256, 0, stream>>>(
        out, xq, (const f4*)mw, fe, re, sel_batch, invn4, score, list, cnt);
    finalize_kernel<<<E_FULL / 256, 256, 0, stream>>>(list, cnt, sel_map, out);
}

// Round 15
// 88.695 us; speedup vs baseline: 1.2407x; 1.2407x over previous
//
#include <hip/hip_runtime.h>

typedef float f4 __attribute__((ext_vector_type(4)));

#define N_SEL   8192
#define N_FEAT  256
#define K_SUB   256
#define N_PERS  4
#define E_FULL  262144
#define E_RAW   262144
#define N_TOTAL 8192
#define EPSILON 0.5f
#define LAMB1   0.5f

// Workspace layout:
#define WS_SCORE_OFF  (128 * 1024)                    // score[K_SUB] f32
#define WS_CNT_OFF    (132 * 1024)                    // pass counter i32
#define WS_XQ_OFF     (256 * 1024)                    // xq[N_SEL][256] fp8 (2 MB)
#define WS_LIST_OFF   (WS_XQ_OFF + 2 * 1024 * 1024)   // list[E_FULL] int2 (2 MB)

// ---- K1: inverse norms + fp8 convert + score + cnt=0 ----
__global__ __launch_bounds__(256) void prep_kernel(const f4* __restrict__ x4,
                                                   const f4* __restrict__ w4,
                                                   float* __restrict__ invn,
                                                   unsigned int* __restrict__ xq,
                                                   const float* __restrict__ s,
                                                   const int* __restrict__ belong,
                                                   float* __restrict__ score,
                                                   int* __restrict__ cnt) {
    __shared__ float sv[K_SUB];
    __shared__ int bv[K_SUB];
    int gid = blockIdx.x * 256 + threadIdx.x;
    int wave = gid >> 6;
    int lane = threadIdx.x & 63;
    int n = wave >> 2;
    int p = wave & 3;
    f4 xv = x4[(size_t)n * 64 + lane];
    f4 wv = w4[p * 64 + lane];
    if (p == 0) {
        // pack 4 dims to 4 fp8 bytes (HW RNE); lane covers dims [4*lane, 4*lane+4)
        int pk = 0;
        pk = __builtin_amdgcn_cvt_pk_fp8_f32(xv.x, xv.y, pk, false);
        pk = __builtin_amdgcn_cvt_pk_fp8_f32(xv.z, xv.w, pk, true);
        xq[(size_t)n * 64 + lane] = (unsigned int)pk;
    }
    f4 h = xv * wv;
    float ss = h.x * h.x + h.y * h.y + h.z * h.z + h.w * h.w;
    #pragma unroll
    for (int off = 32; off; off >>= 1) ss += __shfl_xor(ss, off);
    if (lane == 0) invn[n * 4 + p] = 1.0f / (sqrtf(ss) + 1e-12f);

    if (gid == 0) *cnt = 0;

    if (blockIdx.x == 0) {
        int t = threadIdx.x;
        sv[t] = s[t];
        bv[t] = belong[t];
        __syncthreads();
        int myb = bv[t];
        float sum = 0.0f;
        for (int k = 0; k < K_SUB; ++k)
            if (bv[k] == myb) sum += sv[k];
        score[t] = sv[t] / sum;
    }
}

// ---- K2: zero 1 output row per wave (32x 1KB stores) + 32 cosine edges per
// wave, interleaved 1:1. 64 lanes per edge: one dword (4 fp8 dims) per lane
// per side -> 2 gathers/edge; w^2 table is 16 VGPRs -> high occupancy, so
// gather latency multiplexes under the continuous store stream. No barrier,
// no vmcnt(0) drain. Measured-best structure (R9: 89.3 us).
__global__ __launch_bounds__(256) void zero_edge_kernel(f4* __restrict__ out4,
                                                        const unsigned int* __restrict__ xq,
                                                        const f4* __restrict__ w4,
                                                        const int* __restrict__ fe,
                                                        const int* __restrict__ sel_batch,
                                                        const f4* __restrict__ invn4,
                                                        const float* __restrict__ score,
                                                        int2* __restrict__ list,
                                                        int* __restrict__ cnt) {
    int b = blockIdx.x;                  // 0..2047; block owns rows [4b, 4b+4)
    int t = threadIdx.x;
    int lane = t & 63;
    int w = t >> 6;

    // wave's 32 edges: lanes 0-31 hold i's, lanes 32-63 hold j's
    int ebase = b * 128 + w * 32;
    int myidx = (lane < 32) ? fe[ebase + lane] : fe[E_FULL + ebase + (lane - 32)];

    // per-lane squared weights for dims [4*lane, 4*lane+4), 4 perspectives
    f4 q0 = w4[0 * 64 + lane]; q0 *= q0;
    f4 q1 = w4[1 * 64 + lane]; q1 *= q1;
    f4 q2 = w4[2 * 64 + lane]; q2 *= q2;
    f4 q3 = w4[3 * 64 + lane]; q3 *= q3;

    size_t obase = (size_t)(b * 4 + w) * 2048;   // row base in f4 units
    f4 z = (f4)0.0f;

    // prefetch edge 0
    int ci = __shfl(myidx, 0);
    int cj = __shfl(myidx, 32);
    unsigned int xi = xq[(size_t)ci * 64 + lane];
    unsigned int xj = xq[(size_t)cj * 64 + lane];
    f4 ii = invn4[ci];
    f4 ij = invn4[cj];

    #pragma unroll 4
    for (int s = 0; s < 32; ++s) {
        // one 1KB zero store per step; 32 steps cover the wave's row
        out4[obase + s * 64 + lane] = z;

        // rotate current edge into locals; prefetch next
        int i = ci, j = cj;
        unsigned int ax = xi, bx = xj;
        f4 aii = ii, aij = ij;
        if (s < 31) {
            ci = __shfl(myidx, s + 1);
            cj = __shfl(myidx, 32 + s + 1);
            xi = xq[(size_t)ci * 64 + lane];
            xj = xq[(size_t)cj * 64 + lane];
            ii = invn4[ci];
            ij = invn4[cj];
        }

        // decode fp8 dims (literal selectors required by the builtin)
        float pd0 = __builtin_amdgcn_cvt_f32_fp8((int)ax, 0) *
                    __builtin_amdgcn_cvt_f32_fp8((int)bx, 0);
        float pd1 = __builtin_amdgcn_cvt_f32_fp8((int)ax, 1) *
                    __builtin_amdgcn_cvt_f32_fp8((int)bx, 1);
        float pd2 = __builtin_amdgcn_cvt_f32_fp8((int)ax, 2) *
                    __builtin_amdgcn_cvt_f32_fp8((int)bx, 2);
        float pd3 = __builtin_amdgcn_cvt_f32_fp8((int)ax, 3) *
                    __builtin_amdgcn_cvt_f32_fp8((int)bx, 3);

        float a0 = fmaf(pd3, q0.w, fmaf(pd2, q0.z, fmaf(pd1, q0.y, pd0 * q0.x)));
        float a1 = fmaf(pd3, q1.w, fmaf(pd2, q1.z, fmaf(pd1, q1.y, pd0 * q1.x)));
        float a2 = fmaf(pd3, q2.w, fmaf(pd2, q2.z, fmaf(pd1, q2.y, pd0 * q2.x)));
        float a3 = fmaf(pd3, q3.w, fmaf(pd2, q3.z, fmaf(pd1, q3.y, pd0 * q3.x)));

        float v = a0 * (aii.x * aij.x) + a1 * (aii.y * aij.y) +
                  a2 * (aii.z * aij.z) + a3 * (aii.w * aij.w);
        v += __shfl_xor(v, 1);
        v += __shfl_xor(v, 2);
        v += __shfl_xor(v, 4);
        v += __shfl_xor(v, 8);
        v += __shfl_xor(v, 16);
        v += __shfl_xor(v, 32);

        if (lane == 0 && i != j) {
            v *= 0.25f;
            if (v > EPSILON) {
                float val = v * score[sel_batch[i]] * LAMB1;
                int idx = atomicAdd(cnt, 1);
                int2 ent;
                ent.x = (i << 13) | j;
                ent.y = __float_as_int(val);
                list[idx] = ent;
            }
        }
    }
}

// ---- K3: raw-edge atomics (ordered after K2 by stream dependency) +
//          dedup'd learned-edge scatter ----
__global__ __launch_bounds__(256) void raw_finalize_kernel(const int* __restrict__ re,
                                                           const int2* __restrict__ list,
                                                           const int* __restrict__ cnt,
                                                           const int* __restrict__ sel_map,
                                                           float* __restrict__ out) {
    int t = blockIdx.x * 256 + threadIdx.x;
    if (t < E_RAW) {
        int u = re[t];
        int v = re[E_RAW + t];
        atomicAdd(&out[(size_t)u * N_TOTAL + v], 1.0f - LAMB1);
    }
    int n = *cnt;
    if (t < n) {
        int2 ek = list[t];
        bool first = true;
        for (int l = 0; l < t; ++l)
            if (list[l].x == ek.x) { first = false; break; }
        if (first) {
            int i = ek.x >> 13;
            int j = ek.x & (N_SEL - 1);
            atomicAdd(&out[(size_t)sel_map[i] * N_TOTAL + sel_map[j]],
                      __int_as_float(ek.y));
        }
    }
}

extern "C" void kernel_launch(void* const* d_in, const int* in_sizes, int n_in,
                              void* d_out, int out_size, void* d_ws, size_t ws_size,
                              hipStream_t stream) {
    const float* x         = (const float*)d_in[0];
    const float* mw        = (const float*)d_in[1];
    const int* sel_batch   = (const int*)d_in[2];
    const int* sel_map     = (const int*)d_in[3];
    const int* sel_belong  = (const int*)d_in[4];
    const float* sel_score = (const float*)d_in[5];
    const int* fe          = (const int*)d_in[6];
    const int* re          = (const int*)d_in[7];
    float* out             = (float*)d_out;

    char* ws         = (char*)d_ws;
    float* invn      = (float*)ws;
    float* score     = (float*)(ws + WS_SCORE_OFF);
    int* cnt         = (int*)(ws + WS_CNT_OFF);
    unsigned int* xq = (unsigned int*)(ws + WS_XQ_OFF);
    int2* list       = (int2*)(ws + WS_LIST_OFF);

    prep_kernel<<<8192, 256, 0, stream>>>(
        (const f4*)x, (const f4*)mw, invn, xq, sel_score, sel_belong, score, cnt);
    zero_edge_kernel<<<2048, 256, 0, stream>>>(
        (f4*)out, xq, (const f4*)mw, fe, sel_batch,
        (const f4*)invn, score, list, cnt);
    raw_finalize_kernel<<<1024, 256, 0, stream>>>(re, list, cnt, sel_map, out);
}